// Round 2
// baseline (465.367 us; speedup 1.0000x reference)
//
#include <hip/hip_runtime.h>
#include <hip/hip_bf16.h>

// Problem constants (fixed by the reference)
#define C_INC   32
#define C_OUTC  64
#define KNBR    8
#define BN_EPS  1e-5f

// LDS weight tile: Bt[n][k] transposed, padded (264 shorts = 528 B stride
// == 132 dwords == 4 mod 32 banks) -> b128 fragment reads are 2-way at worst
// (free per m136).
#define BT_STRIDE 264
// partials transposed: [128 stat-rows][NB_PAD block-columns]
#define NB_PAD 1024
// rows per block (8 passes x 4 waves x 16-row tiles)
#define ROWS_PER_BLOCK 512
#define NPASS 8

typedef __bf16 bf16x8 __attribute__((ext_vector_type(8)));
typedef float  floatx4 __attribute__((ext_vector_type(4)));

__device__ inline unsigned short f2bf_bits(float f) {
    unsigned int u = __builtin_bit_cast(unsigned int, f);
    unsigned int r = (u + 0x7FFFu + ((u >> 16) & 1u)) >> 16; // RNE
    return (unsigned short)r;
}
// Hot-path conversion: plain cast -> HW v_cvt (RNE), fewer VALU ops than the
// manual bit-twiddle (m240: scalar cast beats hand-written cvt sequences).
__device__ inline __bf16 f2bf(float f) {
    return (__bf16)f;
}

// ---------------------------------------------------------------------------
// K1: gather + bf16 MFMA conv -> raw out (NO bias: BN's mean-subtract cancels
//     the conv bias exactly; folded into the BN b term), plus per-block
//     channel sum/sumsq partials. The LAST block to finish (device-scope
//     counter, rocPRIM last-block pattern) reduces the partials and writes
//     ab[] directly -- the former stats_kernel dispatch is eliminated, so
//     bn_kernel launches immediately after K1.
// Block = 256 thr = 4 waves; block covers 512 rows (8 passes x 4 waves x 16).
// n_out % 16 == 0 so tile validity is all-or-nothing.
// Neighbor indices are double-buffered: pass p+1's neigh4 loads issue before
// pass p's gathers, so only pass 0 pays the neigh->gather latency chain (and
// that one overlaps the weight-staging barrier).
// ---------------------------------------------------------------------------
__global__ __launch_bounds__(256) void conv_kernel(
    const float* __restrict__ data,      // [N_IN, 32]
    const float* __restrict__ weight,    // [256, 64]
    const int*   __restrict__ neigh,     // [N_OUT, 8]
    const float* __restrict__ gamma,
    const float* __restrict__ beta,
    float*       __restrict__ out,       // raw conv out [N_OUT, 64]
    float*       __restrict__ partialsT, // [128, NB_PAD]
    float*       __restrict__ ab,        // [128] a then b
    int*         __restrict__ counter,   // zeroed before launch
    int n_out, int nb)
{
    __shared__ unsigned short Bt[C_OUTC * BT_STRIDE]; // 33792 B
    __shared__ float red[2 * C_OUTC];                 // 512 B
    __shared__ int amLast;

    const int t    = threadIdx.x;
    const int lane = t & 63;
    const int wave = t >> 6;
    const int m16  = lane & 15;  // A-row in tile / D column (low 4 bits)
    const int q    = lane >> 4;  // quad 0..3

    if (t < 2 * C_OUTC) red[t] = 0.0f;

    const int rowBase = blockIdx.x * ROWS_PER_BLOCK;
    const int4* __restrict__ neigh4 = reinterpret_cast<const int4*>(neigh);

    // Issue pass-0 neighbor loads first so their latency hides under the
    // weight staging + barrier below.
    int4 nA, nB;
    {
        const int arow = rowBase + wave * 16 + m16;
        const int ar = arow < n_out ? arow : 0;
        nA = neigh4[(size_t)ar * 2 + 0];
        nB = neigh4[(size_t)ar * 2 + 1];
    }

    // Stage weights -> LDS transposed bf16 (coalesced global reads).
    {
        const int n = t & 63;
        const int g = t >> 6;
        #pragma unroll 8
        for (int kk = 0; kk < 64; ++kk) {
            int k = kk * 4 + g;
            Bt[n * BT_STRIDE + k] = f2bf_bits(weight[k * C_OUTC + n]);
        }
    }
    __syncthreads();

    float s1[4] = {0.f, 0.f, 0.f, 0.f};
    float s2[4] = {0.f, 0.f, 0.f, 0.f};

    for (int pass = 0; pass < NPASS; ++pass) {
        const int tile0 = rowBase + pass * 64 + wave * 16;

        // Consume current neigh indices; prefetch next pass's immediately.
        const int4 cA = nA, cB = nB;
        if (pass < NPASS - 1) {
            const int arow = rowBase + (pass + 1) * 64 + wave * 16 + m16;
            const int ar = arow < n_out ? arow : 0;
            nA = neigh4[(size_t)ar * 2 + 0];
            nB = neigh4[(size_t)ar * 2 + 1];
        }

        if (tile0 >= n_out) continue;

        floatx4 acc[4];
        #pragma unroll
        for (int nt = 0; nt < 4; ++nt) acc[nt] = (floatx4){0.f, 0.f, 0.f, 0.f};

        int nidxs[KNBR] = {cA.x, cA.y, cA.z, cA.w, cB.x, cB.y, cB.z, cB.w};

        float4 g0[KNBR], g1[KNBR];
        #pragma unroll
        for (int ks = 0; ks < KNBR; ++ks) {
            g0[ks] = (float4){0.f, 0.f, 0.f, 0.f};
            g1[ks] = (float4){0.f, 0.f, 0.f, 0.f};
            if (nidxs[ks] >= 0) {
                const float4* p = reinterpret_cast<const float4*>(
                    data + (size_t)nidxs[ks] * C_INC + q * 8);
                g0[ks] = p[0];
                g1[ks] = p[1];
            }
        }

        #pragma unroll
        for (int ks = 0; ks < KNBR; ++ks) {
            bf16x8 a;
            a[0] = f2bf(g0[ks].x); a[1] = f2bf(g0[ks].y);
            a[2] = f2bf(g0[ks].z); a[3] = f2bf(g0[ks].w);
            a[4] = f2bf(g1[ks].x); a[5] = f2bf(g1[ks].y);
            a[6] = f2bf(g1[ks].z); a[7] = f2bf(g1[ks].w);

            #pragma unroll
            for (int nt = 0; nt < 4; ++nt) {
                const bf16x8 b = *reinterpret_cast<const bf16x8*>(
                    &Bt[(nt * 16 + m16) * BT_STRIDE + ks * 32 + q * 8]);
                acc[nt] = __builtin_amdgcn_mfma_f32_16x16x32_bf16(a, b, acc[nt], 0, 0, 0);
            }
        }

        // Epilogue: store raw (bias folded into BN), accumulate channel stats.
        // D layout: row = q*4 + r, col = m16 + nt*16.
        #pragma unroll
        for (int nt = 0; nt < 4; ++nt) {
            const int c = nt * 16 + m16;
            #pragma unroll
            for (int r = 0; r < 4; ++r) {
                const int drow = tile0 + q * 4 + r;
                const float v = acc[nt][r];
                out[(size_t)drow * C_OUTC + c] = v;
                s1[nt] += v;
                s2[nt] += v * v;
            }
        }
    }

    // Reduce stats over the 4 quads holding each column.
    #pragma unroll
    for (int nt = 0; nt < 4; ++nt) {
        #pragma unroll
        for (int off = 16; off < 64; off <<= 1) {
            s1[nt] += __shfl_xor(s1[nt], off, 64);
            s2[nt] += __shfl_xor(s2[nt], off, 64);
        }
    }
    if (q == 0) {
        #pragma unroll
        for (int nt = 0; nt < 4; ++nt) {
            const int c = nt * 16 + m16;
            atomicAdd(&red[c], s1[nt]);
            atomicAdd(&red[C_OUTC + c], s2[nt]);
        }
    }
    __syncthreads();
    if (t < 2 * C_OUTC) {
        partialsT[(size_t)t * NB_PAD + blockIdx.x] = red[t];
    }

    // ---- last-block stats finalization (replaces the stats_kernel launch) --
    __threadfence();                 // release: make partials device-visible
    __syncthreads();                 // all threads' stores+fences before t0's atomic
    if (t == 0) amLast = (atomicAdd(counter, 1) == nb - 1);
    __syncthreads();
    if (amLast) {
        __threadfence();             // acquire: see every block's partials
        // 256 threads -> 128 stat rows x 2 threads; register-light scalar
        // strided loop so the cold path doesn't inflate main-path VGPRs.
        const int r = t >> 1;
        const int h = t & 1;
        const float* row = partialsT + (size_t)r * NB_PAD;
        float s = 0.f;
        #pragma unroll 4
        for (int b = h; b < nb; b += 2) s += row[b];
        s += __shfl_xor(s, 1, 64);   // combine the pair
        __syncthreads();             // red[] reuse
        if (h == 0) red[r] = s;
        __syncthreads();
        if (t < C_OUTC) {
            const float invN = 1.0f / (float)n_out;
            const float mean = red[t] * invN;               // raw mean (no bias)
            const float var  = red[C_OUTC + t] * invN - mean * mean;
            const float rstd = rsqrtf(var + BN_EPS);
            const float a    = gamma[t] * rstd;
            ab[t]          = a;
            ab[C_OUTC + t] = beta[t] - mean * a;            // conv bias cancels
        }
    }
}

// ---------------------------------------------------------------------------
// K3: in-place affine normalize: y = raw*a[c] + b[c], float4.
// ---------------------------------------------------------------------------
__global__ __launch_bounds__(256) void bn_kernel(
    float* __restrict__ out, const float* __restrict__ ab, long n4)
{
    const long i = (long)blockIdx.x * blockDim.x + threadIdx.x;
    if (i >= n4) return;
    const int c4 = (int)(i & 15); // 64 channels / 4 per float4
    float4 v = reinterpret_cast<float4*>(out)[i];
    const float4 a  = reinterpret_cast<const float4*>(ab)[c4];
    const float4 bb = reinterpret_cast<const float4*>(ab + C_OUTC)[c4];
    v.x = v.x * a.x + bb.x;
    v.y = v.y * a.y + bb.y;
    v.z = v.z * a.z + bb.z;
    v.w = v.w * a.w + bb.w;
    reinterpret_cast<float4*>(out)[i] = v;
}

// ---------------------------------------------------------------------------
extern "C" void kernel_launch(void* const* d_in, const int* in_sizes, int n_in,
                              void* d_out, int out_size, void* d_ws, size_t ws_size,
                              hipStream_t stream) {
    const float* data   = (const float*)d_in[0];
    const float* weight = (const float*)d_in[1];
    // d_in[2] = bias: mathematically cancelled by BN mean-subtraction.
    const float* gamma  = (const float*)d_in[3];
    const float* beta   = (const float*)d_in[4];
    const int*   neigh  = (const int*)d_in[5];

    const int n_out = in_sizes[5] / KNBR; // 250000
    float* out = (float*)d_out;

    const int nb = (n_out + ROWS_PER_BLOCK - 1) / ROWS_PER_BLOCK; // 489 blocks

    // Workspace: partialsT [128*NB_PAD] floats, then ab [128] floats,
    // then the last-block counter (workspace is poisoned, must be zeroed).
    float* partialsT = (float*)d_ws;
    float* ab = partialsT + (size_t)128 * NB_PAD;
    int*   counter = (int*)(ab + 2 * C_OUTC);
    hipMemsetAsync(counter, 0, sizeof(int), stream);

    hipLaunchKernelGGL(conv_kernel, dim3(nb), dim3(256), 0, stream,
                       data, weight, neigh, gamma, beta, out, partialsT, ab,
                       counter, n_out, nb);
    const long n4 = (long)n_out * C_OUTC / 4; // 4,000,000
    hipLaunchKernelGGL(bn_kernel, dim3((unsigned)((n4 + 255) / 256)), dim3(256), 0, stream,
                       out, ab, n4);
}

// Round 3
// 379.884 us; speedup vs baseline: 1.2250x; 1.2250x over previous
//
#include <hip/hip_runtime.h>
#include <hip/hip_bf16.h>

// Problem constants (fixed by the reference)
#define C_INC   32
#define C_OUTC  64
#define KNBR    8
#define BN_EPS  1e-5f

// LDS weight tile: Bt[n][k] transposed, padded (264 shorts = 528 B stride
// == 132 dwords == 4 mod 32 banks) -> b128 fragment reads are 2-way at worst
// (free per m136).
#define BT_STRIDE 264
// partials transposed: [128 stat-rows][NB_PAD block-columns]
#define NB_PAD 1024
// rows per block (4 passes x 4 waves x 16-row tiles) -> 977 blocks,
// ~4 blocks/CU for latency hiding. (512 rows/block = 489 blocks measured
// neutral-to-worse; the fused last-block variant collapsed VGPRs to 56 and
// destroyed gather MLP -- reverted.)
#define ROWS_PER_BLOCK 256
#define NPASS 4

typedef __bf16 bf16x8 __attribute__((ext_vector_type(8)));
typedef float  floatx4 __attribute__((ext_vector_type(4)));

__device__ inline unsigned short f2bf_bits(float f) {
    unsigned int u = __builtin_bit_cast(unsigned int, f);
    unsigned int r = (u + 0x7FFFu + ((u >> 16) & 1u)) >> 16; // RNE
    return (unsigned short)r;
}
// Hot-path conversion: plain cast -> HW v_cvt (RNE), fewer VALU ops than the
// manual bit-twiddle (m240: scalar cast beats hand-written cvt sequences).
__device__ inline __bf16 f2bf(float f) {
    return (__bf16)f;
}

// ---------------------------------------------------------------------------
// K1: gather + bf16 MFMA conv -> raw out (NO bias: BN's mean-subtract cancels
//     the conv bias exactly, folded into K2's b term), plus per-block channel
//     sum/sumsq partials written TRANSPOSED (contiguous for K2).
// Block = 256 thr = 4 waves; block covers 256 rows (4 passes x 4 waves x 16).
// n_out % 16 == 0 so tile validity is all-or-nothing.
// Neighbor indices are double-buffered: pass p+1's neigh4 loads issue before
// pass p's gathers, so only pass 0 pays the neigh->gather latency chain (and
// that one overlaps the weight-staging barrier).
// NOTE: keep this kernel's tail minimal. A fused "last block does the stats"
// variant (threadfence + atomic counter) made the register allocator shrink
// the kernel to 56 VGPRs, serializing the 16-load gather burst: 50 -> 180 us.
// ---------------------------------------------------------------------------
__global__ __launch_bounds__(256) void conv_kernel(
    const float* __restrict__ data,      // [N_IN, 32]
    const float* __restrict__ weight,    // [256, 64]
    const int*   __restrict__ neigh,     // [N_OUT, 8]
    float*       __restrict__ out,       // raw conv out [N_OUT, 64]
    float*       __restrict__ partialsT, // [128, NB_PAD]
    int n_out)
{
    __shared__ unsigned short Bt[C_OUTC * BT_STRIDE]; // 33792 B
    __shared__ float red[2 * C_OUTC];                 // 512 B

    const int t    = threadIdx.x;
    const int lane = t & 63;
    const int wave = t >> 6;
    const int m16  = lane & 15;  // A-row in tile / D column (low 4 bits)
    const int q    = lane >> 4;  // quad 0..3

    if (t < 2 * C_OUTC) red[t] = 0.0f;

    const int rowBase = blockIdx.x * ROWS_PER_BLOCK;
    const int4* __restrict__ neigh4 = reinterpret_cast<const int4*>(neigh);

    // Issue pass-0 neighbor loads first so their latency hides under the
    // weight staging + barrier below.
    int4 nA, nB;
    {
        const int arow = rowBase + wave * 16 + m16;
        const int ar = arow < n_out ? arow : 0;
        nA = neigh4[(size_t)ar * 2 + 0];
        nB = neigh4[(size_t)ar * 2 + 1];
    }

    // Stage weights -> LDS transposed bf16 (coalesced global reads).
    {
        const int n = t & 63;
        const int g = t >> 6;
        #pragma unroll 8
        for (int kk = 0; kk < 64; ++kk) {
            int k = kk * 4 + g;
            Bt[n * BT_STRIDE + k] = f2bf_bits(weight[k * C_OUTC + n]);
        }
    }
    __syncthreads();

    float s1[4] = {0.f, 0.f, 0.f, 0.f};
    float s2[4] = {0.f, 0.f, 0.f, 0.f};

    for (int pass = 0; pass < NPASS; ++pass) {
        const int tile0 = rowBase + pass * 64 + wave * 16;

        // Consume current neigh indices; prefetch next pass's immediately.
        const int4 cA = nA, cB = nB;
        if (pass < NPASS - 1) {
            const int arow = rowBase + (pass + 1) * 64 + wave * 16 + m16;
            const int ar = arow < n_out ? arow : 0;
            nA = neigh4[(size_t)ar * 2 + 0];
            nB = neigh4[(size_t)ar * 2 + 1];
        }

        if (tile0 >= n_out) continue;

        floatx4 acc[4];
        #pragma unroll
        for (int nt = 0; nt < 4; ++nt) acc[nt] = (floatx4){0.f, 0.f, 0.f, 0.f};

        int nidxs[KNBR] = {cA.x, cA.y, cA.z, cA.w, cB.x, cB.y, cB.z, cB.w};

        float4 g0[KNBR], g1[KNBR];
        #pragma unroll
        for (int ks = 0; ks < KNBR; ++ks) {
            g0[ks] = (float4){0.f, 0.f, 0.f, 0.f};
            g1[ks] = (float4){0.f, 0.f, 0.f, 0.f};
            if (nidxs[ks] >= 0) {
                const float4* p = reinterpret_cast<const float4*>(
                    data + (size_t)nidxs[ks] * C_INC + q * 8);
                g0[ks] = p[0];
                g1[ks] = p[1];
            }
        }

        #pragma unroll
        for (int ks = 0; ks < KNBR; ++ks) {
            bf16x8 a;
            a[0] = f2bf(g0[ks].x); a[1] = f2bf(g0[ks].y);
            a[2] = f2bf(g0[ks].z); a[3] = f2bf(g0[ks].w);
            a[4] = f2bf(g1[ks].x); a[5] = f2bf(g1[ks].y);
            a[6] = f2bf(g1[ks].z); a[7] = f2bf(g1[ks].w);

            #pragma unroll
            for (int nt = 0; nt < 4; ++nt) {
                const bf16x8 b = *reinterpret_cast<const bf16x8*>(
                    &Bt[(nt * 16 + m16) * BT_STRIDE + ks * 32 + q * 8]);
                acc[nt] = __builtin_amdgcn_mfma_f32_16x16x32_bf16(a, b, acc[nt], 0, 0, 0);
            }
        }

        // Epilogue: store raw (bias folded into BN), accumulate channel stats.
        // D layout: row = q*4 + r, col = m16 + nt*16.
        #pragma unroll
        for (int nt = 0; nt < 4; ++nt) {
            const int c = nt * 16 + m16;
            #pragma unroll
            for (int r = 0; r < 4; ++r) {
                const int drow = tile0 + q * 4 + r;
                const float v = acc[nt][r];
                out[(size_t)drow * C_OUTC + c] = v;
                s1[nt] += v;
                s2[nt] += v * v;
            }
        }
    }

    // Reduce stats over the 4 quads holding each column.
    #pragma unroll
    for (int nt = 0; nt < 4; ++nt) {
        #pragma unroll
        for (int off = 16; off < 64; off <<= 1) {
            s1[nt] += __shfl_xor(s1[nt], off, 64);
            s2[nt] += __shfl_xor(s2[nt], off, 64);
        }
    }
    if (q == 0) {
        #pragma unroll
        for (int nt = 0; nt < 4; ++nt) {
            const int c = nt * 16 + m16;
            atomicAdd(&red[c], s1[nt]);
            atomicAdd(&red[C_OUTC + c], s2[nt]);
        }
    }
    __syncthreads();
    if (t < 2 * C_OUTC) {
        partialsT[(size_t)t * NB_PAD + blockIdx.x] = red[t];
    }
}

// ---------------------------------------------------------------------------
// K2: 64 blocks; block c reduces channel c's raw sum (row c) and sumsq
//     (row 64+c) over nb contiguous floats. Stats are of the UNBIASED conv;
//     since BN subtracts the mean, the conv bias cancels exactly:
//       y = raw*a + (beta - mean_raw*a),  a = gamma*rstd,
//       var(raw) == var(raw + bias).
// ---------------------------------------------------------------------------
__global__ __launch_bounds__(256) void stats_kernel(
    const float* __restrict__ partialsT, int nb,
    const float* __restrict__ gamma, const float* __restrict__ beta,
    float* __restrict__ ab, int n_out)
{
    const int t    = threadIdx.x;
    const int lane = t & 63;
    const int wave = t >> 6;
    const int c    = blockIdx.x;

    float sA = 0.f, sB = 0.f;
    for (int b = t; b < nb; b += 256) {
        sA += partialsT[(size_t)c * NB_PAD + b];
        sB += partialsT[(size_t)(C_OUTC + c) * NB_PAD + b];
    }
    #pragma unroll
    for (int off = 1; off < 64; off <<= 1) {
        sA += __shfl_xor(sA, off, 64);
        sB += __shfl_xor(sB, off, 64);
    }
    __shared__ float red[8];
    if (lane == 0) { red[wave] = sA; red[4 + wave] = sB; }
    __syncthreads();
    if (t == 0) {
        const float S1 = (red[0] + red[1]) + (red[2] + red[3]);
        const float S2 = (red[4] + red[5]) + (red[6] + red[7]);
        const float invN = 1.0f / (float)n_out;
        const float mean = S1 * invN;                  // mean of raw (no bias)
        const float var  = S2 * invN - mean * mean;    // shift-invariant
        const float rstd = rsqrtf(var + BN_EPS);
        const float a    = gamma[c] * rstd;
        ab[c]          = a;
        ab[C_OUTC + c] = beta[c] - mean * a;           // conv bias cancels
    }
}

// ---------------------------------------------------------------------------
// K3: in-place affine normalize: y = raw*a[c] + b[c], float4.
// ---------------------------------------------------------------------------
__global__ __launch_bounds__(256) void bn_kernel(
    float* __restrict__ out, const float* __restrict__ ab, long n4)
{
    const long i = (long)blockIdx.x * blockDim.x + threadIdx.x;
    if (i >= n4) return;
    const int c4 = (int)(i & 15); // 64 channels / 4 per float4
    float4 v = reinterpret_cast<float4*>(out)[i];
    const float4 a  = reinterpret_cast<const float4*>(ab)[c4];
    const float4 bb = reinterpret_cast<const float4*>(ab + C_OUTC)[c4];
    v.x = v.x * a.x + bb.x;
    v.y = v.y * a.y + bb.y;
    v.z = v.z * a.z + bb.z;
    v.w = v.w * a.w + bb.w;
    reinterpret_cast<float4*>(out)[i] = v;
}

// ---------------------------------------------------------------------------
extern "C" void kernel_launch(void* const* d_in, const int* in_sizes, int n_in,
                              void* d_out, int out_size, void* d_ws, size_t ws_size,
                              hipStream_t stream) {
    const float* data   = (const float*)d_in[0];
    const float* weight = (const float*)d_in[1];
    // d_in[2] = bias: mathematically cancelled by BN mean-subtraction.
    const float* gamma  = (const float*)d_in[3];
    const float* beta   = (const float*)d_in[4];
    const int*   neigh  = (const int*)d_in[5];

    const int n_out = in_sizes[5] / KNBR; // 250000
    float* out = (float*)d_out;

    const int nb = (n_out + ROWS_PER_BLOCK - 1) / ROWS_PER_BLOCK; // 977 blocks

    // Workspace: partialsT [128*NB_PAD] floats, then ab [128] floats.
    float* partialsT = (float*)d_ws;
    float* ab = partialsT + (size_t)128 * NB_PAD;

    hipLaunchKernelGGL(conv_kernel, dim3(nb), dim3(256), 0, stream,
                       data, weight, neigh, out, partialsT, n_out);
    hipLaunchKernelGGL(stats_kernel, dim3(C_OUTC), dim3(256), 0, stream,
                       partialsT, nb, gamma, beta, ab, n_out);
    const long n4 = (long)n_out * C_OUTC / 4; // 4,000,000
    hipLaunchKernelGGL(bn_kernel, dim3((unsigned)((n4 + 255) / 256)), dim3(256), 0, stream,
                       out, ab, n4);
}